// Round 11
// baseline (677.253 us; speedup 1.0000x reference)
//
#include <hip/hip_runtime.h>
#include <hip/hip_bf16.h>
#include <stdint.h>

#define TSEQ   2048
#define DMODEL 6144
#define NHEADS 48
#define NKVH   8
#define HDIM   128
#define QKVC   8192   // (48 + 2*8) * 128
#define GRP    6      // NHEADS / NKVH

typedef __attribute__((ext_vector_type(8))) short short8;
typedef __attribute__((ext_vector_type(4))) float f32x4;

// ---------- helpers ----------

__device__ __forceinline__ unsigned short f2b(float f) {
  union { float f; unsigned int u; } v; v.f = f;
  unsigned int u = v.u;
  unsigned int r = (u + 0x7FFFu + ((u >> 16) & 1u)) >> 16;  // RNE
  return (unsigned short)r;
}

__device__ __forceinline__ float b2f(unsigned short s) {
  union { unsigned int u; float f; } v; v.u = ((unsigned int)s) << 16;
  return v.f;
}

#if __has_builtin(__builtin_amdgcn_exp2f)
#define EXP2(x) __builtin_amdgcn_exp2f(x)
#else
#define EXP2(x) exp2f(x)
#endif
#if __has_builtin(__builtin_amdgcn_rcpf)
#define RCP(x) __builtin_amdgcn_rcpf(x)
#else
#define RCP(x) (1.0f / (x))
#endif

typedef const __attribute__((address_space(1))) void* as1_cvp;
typedef __attribute__((address_space(3))) void* as3_vp;

__device__ __forceinline__ void gload_lds16(const void* g, void* l) {
  // LDS dest is wave-uniform base + lane*16 (layouts below are linear in tid)
  __builtin_amdgcn_global_load_lds(
      (as1_cvp)(uintptr_t)g,
      (as3_vp)(unsigned int)(uintptr_t)l, 16, 0, 0);
}

#define LGKMC(n) do { asm volatile("s_waitcnt lgkmcnt(" #n ")" ::: "memory"); \
                      __builtin_amdgcn_sched_barrier(0); } while (0)
#define VMC(n) do { asm volatile("s_waitcnt vmcnt(" #n ")" ::: "memory"); \
                    __builtin_amdgcn_sched_barrier(0); } while (0)
#define BARR  do { asm volatile("s_barrier" ::: "memory"); } while (0)

// ---------- prep kernels ----------

__global__ __launch_bounds__(256) void k_cvt(const float* __restrict__ in,
                                             unsigned short* __restrict__ outp, int n) {
  int i = (blockIdx.x * 256 + threadIdx.x) * 8;
  if (i + 7 < n) {
    float4 va = *(const float4*)(in + i);
    float4 vb = *(const float4*)(in + i + 4);
    union { unsigned short s[8]; uint4 u; } o;
    o.s[0] = f2b(va.x); o.s[1] = f2b(va.y); o.s[2] = f2b(va.z); o.s[3] = f2b(va.w);
    o.s[4] = f2b(vb.x); o.s[5] = f2b(vb.y); o.s[6] = f2b(vb.z); o.s[7] = f2b(vb.w);
    *(uint4*)(outp + i) = o.u;
  }
}

// f32 -> bf16 64x64 tile transpose: out[c][r] = in[r][c]
__global__ __launch_bounds__(256) void k_tr2(const float* __restrict__ in, long istr, long zin,
                                             unsigned short* __restrict__ out, long ostr, long zout) {
  __shared__ unsigned short tile[64][68];
  const int tid = threadIdx.x;
  const int br = blockIdx.y * 64;      // input row base
  const int bc = blockIdx.x * 64;      // input col base
  in  += (size_t)blockIdx.z * zin;
  out += (size_t)blockIdx.z * zout;
  const int row = tid >> 4;            // 0..15
  const int c4  = (tid & 15) * 4;
#pragma unroll
  for (int p = 0; p < 4; ++p) {
    const int r = p * 16 + row;
    float4 v = *(const float4*)(in + (size_t)(br + r) * istr + bc + c4);
    tile[r][c4 + 0] = f2b(v.x);
    tile[r][c4 + 1] = f2b(v.y);
    tile[r][c4 + 2] = f2b(v.z);
    tile[r][c4 + 3] = f2b(v.w);
  }
  __syncthreads();
#pragma unroll
  for (int p = 0; p < 4; ++p) {
    const int r = p * 16 + row;        // out row (= input col index)
    union { unsigned short s[4]; uint2 u; } o;
    o.s[0] = tile[c4 + 0][r];
    o.s[1] = tile[c4 + 1][r];
    o.s[2] = tile[c4 + 2][r];
    o.s[3] = tile[c4 + 3][r];
    *(uint2*)(out + (size_t)(bc + r) * ostr + br + c4) = o.u;
  }
}

// bf16 -> bf16 64x64 tile transpose: out[c][r] = in[r][c]
__global__ __launch_bounds__(256) void k_tr2b(const unsigned short* __restrict__ in, long istr, long zin,
                                              unsigned short* __restrict__ out, long ostr, long zout) {
  __shared__ unsigned short tile[64][68];
  const int tid = threadIdx.x;
  const int br = blockIdx.y * 64;
  const int bc = blockIdx.x * 64;
  in  += (size_t)blockIdx.z * zin;
  out += (size_t)blockIdx.z * zout;
  const int row = tid >> 4;            // 0..15
  const int c4  = (tid & 15) * 4;
#pragma unroll
  for (int p = 0; p < 4; ++p) {
    const int r = p * 16 + row;
    union { unsigned short s[4]; uint2 u; } v;
    v.u = *(const uint2*)(in + (size_t)(br + r) * istr + bc + c4);
    tile[r][c4 + 0] = v.s[0];
    tile[r][c4 + 1] = v.s[1];
    tile[r][c4 + 2] = v.s[2];
    tile[r][c4 + 3] = v.s[3];
  }
  __syncthreads();
#pragma unroll
  for (int p = 0; p < 4; ++p) {
    const int r = p * 16 + row;
    union { unsigned short s[4]; uint2 u; } o;
    o.s[0] = tile[c4 + 0][r];
    o.s[1] = tile[c4 + 1][r];
    o.s[2] = tile[c4 + 2][r];
    o.s[3] = tile[c4 + 3][r];
    *(uint2*)(out + (size_t)(bc + r) * ostr + br + c4) = o.u;
  }
}

__global__ void k_trig(const int* __restrict__ pos, float* __restrict__ cs,
                       float* __restrict__ sn) {
  int t = blockIdx.x, i = threadIdx.x;  // block=64
  float p = (float)pos[t];
  float inv = EXP2(-(float)(2 * i) * (1.0f / 128.0f) * 13.287712379549449f);
  float f = p * inv;
  cs[t * 64 + i] = cosf(f);
  sn[t * 64 + i] = sinf(f);
}

// ---------- GEMM 256x256x64: round-9 schedule (best verified: 179us, 0 conflicts) ----------
// A[M][K] bf16 row-major, Bt[N][K] bf16, C[M][N] f32 or bf16.
// 512 thr = 8 waves (2M x 4N); per-wave out 128x64 = acc[8][4] f32x4.
// LDS (dynamic 128 KiB): buf b at b*65536: A 256 rows x 128 B (XOR-swizzled
// byte^=(row&7)<<4), B at +32768 same.
// Per tile t (buf cur=t&1): issue ALL 24 ds_reads up-front (a0,b0 | b1 | a1),
// STAGE_B(t+1) interleaved; consume with counted lgkmcnt; 2 barriers/tile:
//   lgkm(12) MFMA(0,0); lgkm(8) MFMA(0,1); lgkm(0) MFMA(1,0);
//   BARR; STAGE_A(t+2,cur); MFMA(1,1); vmcnt(4); BARR
// Ledger: vmcnt(4) leaves A(t+2) in flight; A(t+1), B(t+1) landed. lgkm(0)
// precedes mid-BARR so all reads of buf cur drain before STAGE_A overwrites.

#define READ_A(mh, aa) do { \
  _Pragma("unroll") for (int m = 0; m < 4; ++m) \
  _Pragma("unroll") for (int ks = 0; ks < 2; ++ks) \
    aa[m][ks] = *(const short8*)(LA + (wm * 128 + (mh) * 64 + m * 16 + lr) * 128 \
                                 + ((ks * 64 + lkb) ^ lsw)); } while (0)

#define READ_B(nh, bb) do { \
  _Pragma("unroll") for (int n2 = 0; n2 < 2; ++n2) \
  _Pragma("unroll") for (int ks = 0; ks < 2; ++ks) \
    bb[n2][ks] = *(const short8*)(LB + (wn * 64 + (nh) * 32 + n2 * 16 + lr) * 128 \
                                  + ((ks * 64 + lkb) ^ lsw)); } while (0)

#define CLUSTER(mh, nh, aa, bb) do { \
  __builtin_amdgcn_s_setprio(1); \
  _Pragma("unroll") for (int m = 0; m < 4; ++m) \
  _Pragma("unroll") for (int n2 = 0; n2 < 2; ++n2) \
  _Pragma("unroll") for (int ks = 0; ks < 2; ++ks) \
    acc[(mh) * 4 + m][(nh) * 2 + n2] = __builtin_amdgcn_mfma_f32_16x16x32_bf16( \
        aa[m][ks], bb[n2][ks], acc[(mh) * 4 + m][(nh) * 2 + n2], 0, 0, 0); \
  __builtin_amdgcn_s_setprio(0); } while (0)

#define STAGE_A(kt, bb) do { \
  _Pragma("unroll") for (int i = 0; i < 4; ++i) \
    gload_lds16(Asrc + (size_t)(kt) * 64 + (size_t)i * 64 * K, \
                lds + (bb) * 65536 + F + i * 8192); } while (0)

#define STAGE_B(kt, bb) do { \
  _Pragma("unroll") for (int i = 0; i < 4; ++i) \
    gload_lds16(Bsrc + (size_t)(kt) * 64 + (size_t)i * 64 * K, \
                lds + (bb) * 65536 + 32768 + F + i * 8192); } while (0)

template <typename OutT>
__global__ __launch_bounds__(512, 2) void k_gemm8(const unsigned short* __restrict__ A,
                                                  const unsigned short* __restrict__ Bt,
                                                  OutT* __restrict__ C,
                                                  int M, int N, int K) {
  extern __shared__ __align__(16) unsigned char lds[];
  const int tid  = threadIdx.x;
  const int lane = tid & 63;
  const int wave = tid >> 6;
  const int wm = wave >> 2;           // 0..1
  const int wn = wave & 3;            // 0..3
  const int lr  = lane & 15;
  const int lkb = (lane >> 4) * 16;
  const int li4 = (lane >> 4) * 4;
  const int lsw = (lane & 7) << 4;    // read-side swizzle const

  // XCD n-stripe mapping: xcd = lin&7 owns n-cols [xcd*Cx, (xcd+1)*Cx)
  const int mt = M >> 8;
  const int nt = N >> 8;
  const int Cx = nt >> 3;
  const int lin = blockIdx.x;
  const int xcd = lin & 7;
  const int r   = lin >> 3;
  const int m0  = (r % mt) << 8;
  const int n0  = (xcd * Cx + r / mt) << 8;

  // staging: thread's 16B chunk; row advances 64 per load index
  const int F   = tid * 16;
  const int r0  = F >> 7;
  const int cbs = (F & 127) ^ ((r0 & 7) << 4);   // pre-swizzled source col
  const unsigned short* Asrc = A  + (size_t)(m0 + r0) * K + (cbs >> 1);
  const unsigned short* Bsrc = Bt + (size_t)(n0 + r0) * K + (cbs >> 1);

  const int NT = K >> 6;

  f32x4 acc[8][4];
#pragma unroll
  for (int i = 0; i < 8; ++i)
#pragma unroll
    for (int j = 0; j < 4; ++j) acc[i][j] = (f32x4){0.f, 0.f, 0.f, 0.f};

  // prologue: A(0),B(0)->buf0, A(1)->buf1; wait first 8, keep A(1) flying
  STAGE_A(0, 0);
  STAGE_B(0, 0);
  STAGE_A(1, 1);
  VMC(4);
  BARR;

  for (int t = 0; t < NT; ++t) {
    const int cur = t & 1;
    const unsigned char* LA = lds + cur * 65536;
    const unsigned char* LB = LA + 32768;
    short8 a0[4][2], a1[4][2], b0[2][2], b1[2][2];

    // issue all reads up-front; stage B(t+1) interleaved
    READ_A(0, a0);                       // 8  (lgkm 8)
    READ_B(0, b0);                       // 4  (lgkm 12)
    if (t + 1 < NT) STAGE_B(t + 1, cur ^ 1);
    READ_B(1, b1);                       // 4  (lgkm 16)
    READ_A(1, a1);                       // 8  (lgkm 24)

    LGKMC(12);                           // a0,b0 landed
    CLUSTER(0, 0, a0, b0);
    LGKMC(8);                            // b1 landed
    CLUSTER(0, 1, a0, b1);
    LGKMC(0);                            // a1 landed (all reads drained)
    CLUSTER(1, 0, a1, b0);
    BARR;                                // all waves drained -> safe to overwrite A(cur)
    if (t + 2 < NT) STAGE_A(t + 2, cur);
    CLUSTER(1, 1, a1, b1);               // register-only, overlaps stage
    if (t + 2 < NT) { VMC(4); } else { VMC(0); }
    BARR;
  }

#pragma unroll
  for (int mh = 0; mh < 2; ++mh)
#pragma unroll
    for (int m = 0; m < 4; ++m)
#pragma unroll
      for (int nh = 0; nh < 2; ++nh)
#pragma unroll
        for (int n2 = 0; n2 < 2; ++n2)
#pragma unroll
          for (int i = 0; i < 4; ++i) {
            int row = m0 + wm * 128 + mh * 64 + m * 16 + li4 + i;
            int col = n0 + wn * 64 + nh * 32 + n2 * 16 + lr;
            float v = acc[mh * 4 + m][nh * 2 + n2][i];
            if constexpr (sizeof(OutT) == 2)
              C[(size_t)row * N + col] = (OutT)f2b(v);
            else
              C[(size_t)row * N + col] = (OutT)v;
          }
}

// ---------- RoPE + split: QKV bf16 [T][8192] -> Q[h][t][d], K[h][t][d] (bf16) ----------

__global__ __launch_bounds__(256) void k_rope(const unsigned short* __restrict__ qkv,
                                              const float* __restrict__ cs,
                                              const float* __restrict__ sn,
                                              unsigned short* __restrict__ Q,
                                              unsigned short* __restrict__ K) {
  const int t = blockIdx.x;
  const int tid = threadIdx.x;
  const unsigned short* row = qkv + (size_t)t * QKVC;
  const float* c = cs + t * 64;
  const float* s = sn + t * 64;
  for (int p = tid; p < 56 * 16; p += 256) {
    const int h = p >> 4, q4 = (p & 15) * 4;
    const unsigned short* src = row + h * 128;
    union { unsigned short sh[4]; uint2 u; } x1u, x2u;
    x1u.u = *(const uint2*)(src + q4);
    x2u.u = *(const uint2*)(src + 64 + q4);
    float4 cc = *(const float4*)(c + q4);
    float4 ss = *(const float4*)(s + q4);
    unsigned short* dst = (h < NHEADS)
        ? Q + ((size_t)h * TSEQ + t) * HDIM
        : K + ((size_t)(h - NHEADS) * TSEQ + t) * HDIM;
    float x10 = b2f(x1u.sh[0]), x11 = b2f(x1u.sh[1]),
          x12 = b2f(x1u.sh[2]), x13 = b2f(x1u.sh[3]);
    float x20 = b2f(x2u.sh[0]), x21 = b2f(x2u.sh[1]),
          x22 = b2f(x2u.sh[2]), x23 = b2f(x2u.sh[3]);
    union { unsigned short sh[4]; uint2 u; } o1, o2;
    o1.sh[0] = f2b(x10 * cc.x - x20 * ss.x);
    o1.sh[1] = f2b(x11 * cc.y - x21 * ss.y);
    o1.sh[2] = f2b(x12 * cc.z - x22 * ss.z);
    o1.sh[3] = f2b(x13 * cc.w - x23 * ss.w);
    o2.sh[0] = f2b(x20 * cc.x + x10 * ss.x);
    o2.sh[1] = f2b(x21 * cc.y + x11 * ss.y);
    o2.sh[2] = f2b(x22 * cc.z + x12 * ss.z);
    o2.sh[3] = f2b(x23 * cc.w + x13 * ss.w);
    *(uint2*)(dst + q4) = o1.u;
    *(uint2*)(dst + 64 + q4) = o2.u;
  }
}

// ---------- attention: balanced pairs + T14 async reg-staging ----------
// Per kv-step: K/V for step st+1 are loaded global->REG before computing
// step st (HBM/L2 latency hides under QK+softmax+PV ~500cyc), then written
// reg->LDS at the top of the next iteration (after the trailing barrier has
// proven all readers of the LDS buffer done — same 2-barrier invariant as
// the gload_lds version). Global reads are linear/coalesced; the XOR swizzle
// byte^=(row&7)<<4 is applied on the ds_write address and matched on reads.

__global__ __launch_bounds__(256, 3) void k_attn2(const unsigned short* __restrict__ Q,
                                                  const unsigned short* __restrict__ K,
                                                  const unsigned short* __restrict__ V,  // Vt[h][d][t]
                                                  unsigned short* __restrict__ O) {
  __shared__ __align__(16) unsigned char KsB[16384];      // 64 s-rows x 256 B (swizzled)
  __shared__ __align__(16) unsigned char VsB[16384];      // 128 d-rows x 128 B (swizzled)
  __shared__ __align__(16) unsigned char PsB[4][2048];    // per-wave 16 q-rows x 128 B (swizzled)

  const int lin = blockIdx.x;
  const int g   = lin & 7;            // kv head == XCD hint
  const int rr  = lin >> 3;           // 0..95
  const int hg  = rr % 6;
  const int pr  = rr / 6;             // 0..15
  const int h   = g * 6 + hg;
  const int tid = threadIdx.x, wave = tid >> 6, lane = tid & 63;
  const int lr = lane & 15, lk = (lane >> 4) * 8, li4 = (lane >> 4) * 4;
  const unsigned short* Qh = Q + (size_t)h * (TSEQ * HDIM);
  const unsigned char*  Kb = (const unsigned char*)(K + (size_t)g * (TSEQ * HDIM));
  const unsigned char*  Vb = (const unsigned char*)(V + (size_t)g * (TSEQ * HDIM));
  unsigned char* Pw = PsB[wave];

  // per-thread staging geometry (c = 0..3): FF = tid*16 + c*4096
  // K: krow = FF>>8 (0..63),  kcol = FF&255; V: vrow = FF>>7, vcol = FF&127

  for (int half = 0; half < 2; ++half) {
    const int j  = half ? (31 - pr) : pr;     // q-tile index (64 rows)
    const int t0 = j * 64 + wave * 16;        // this wave's 16 rows
    const int nst = j + 1;

    short8 qf[4];
#pragma unroll
    for (int ks = 0; ks < 4; ++ks)
      qf[ks] = *(const short8*)(Qh + (size_t)(t0 + lr) * HDIM + ks * 32 + lk);

    f32x4 oacc[8];
#pragma unroll
    for (int n = 0; n < 8; ++n) oacc[n] = (f32x4){0.f, 0.f, 0.f, 0.f};
    float rs4[4] = {0.f, 0.f, 0.f, 0.f};

    uint4 kreg[4], vreg[4];
    // prologue: issue loads for st = 0
#pragma unroll
    for (int c = 0; c < 4; ++c) {
      const int FF = tid * 16 + c * 4096;
      kreg[c] = *(const uint4*)(Kb + (size_t)(FF >> 8) * 256 + (FF & 255));
      vreg[c] = *(const uint4*)(Vb + (size_t)(FF >> 7) * (TSEQ * 2) + (FF & 127));
    }

    for (int st = 0; st < nst; ++st) {
      // write staged regs -> LDS (prev step's readers done at trailing barrier)
#pragma unroll
      for (int c = 0; c < 4; ++c) {
        const int FF = tid * 16 + c * 4096;
        const int krow = FF >> 8, kcol = FF & 255;
        *(uint4*)(KsB + krow * 256 + (kcol ^ ((krow & 7) << 4))) = kreg[c];
        const int vrow = FF >> 7, vcol = FF & 127;
        *(uint4*)(VsB + vrow * 128 + (vcol ^ ((vrow & 7) << 4))) = vreg[c];
      }
      // issue next step's loads; they land during this step's compute
      if (st + 1 < nst) {
        const int s1 = (st + 1) * 64;
#pragma unroll
        for (int c = 0; c < 4; ++c) {
          const int FF = tid * 16 + c * 4096;
          kreg[c] = *(const uint4*)(Kb + (size_t)(s1 + (FF >> 8)) * 256 + (FF & 255));
          vreg[c] = *(const uint4*)(Vb + (size_t)(FF >> 7) * (TSEQ * 2) +
                                    (size_t)s1 * 2 + (FF & 127));
        }
      }
      __syncthreads();

      const int s0 = st * 64;
      f32x4 sacc[4];
#pragma unroll
      for (int n = 0; n < 4; ++n) sacc[n] = (f32x4){0.f, 0.f, 0.f, 0.f};
#pragma unroll
      for (int ks = 0; ks < 4; ++ks) {
        short8 kf[4];
#pragma unroll
        for (int n = 0; n < 4; ++n) {
          const int row = n * 16 + lr;
          kf[n] = *(const short8*)(KsB + row * 256 + ((ks * 64 + lk * 2) ^ ((row & 7) << 4)));
        }
#pragma unroll
        for (int n = 0; n < 4; ++n)
          sacc[n] = __builtin_amdgcn_mfma_f32_16x16x32_bf16(qf[ks], kf[n], sacc[n], 0, 0, 0);
      }

      const bool lastst = (st == nst - 1);
#pragma unroll
      for (int n = 0; n < 4; ++n)
#pragma unroll
        for (int i = 0; i < 4; ++i) {
          float sv = sacc[n][i] * 0.08838834764831845f;   // 1/sqrt(128)
          float e = EXP2(sv * 0.09617966939259757f);       // e^(s/15)
          float p = EXP2(-86.5617024533378f * RCP(e + 1.0f));
          if (lastst && (s0 + n * 16 + lr > t0 + li4 + i)) p = 0.f;
          rs4[i] += p;
          const int prow = li4 + i;
          *(unsigned short*)(Pw + prow * 128 +
              (((n * 16 + lr) * 2) ^ ((prow & 7) << 4))) = f2b(p);
        }

#pragma unroll
      for (int ks2 = 0; ks2 < 2; ++ks2) {
        short8 pf = *(const short8*)(Pw + lr * 128 +
                         (((ks2 * 32 + lk) * 2) ^ ((lr & 7) << 4)));
        short8 vf[8];
#pragma unroll
        for (int n = 0; n < 8; ++n) {
          const int row = n * 16 + lr;
          vf[n] = *(const short8*)(VsB + row * 128 + ((ks2 * 64 + lk * 2) ^ ((row & 7) << 4)));
        }
#pragma unroll
        for (int n = 0; n < 8; ++n)
          oacc[n] = __builtin_amdgcn_mfma_f32_16x16x32_bf16(pf, vf[n], oacc[n], 0, 0, 0);
      }
      __syncthreads();   // all readers of KsB/VsB done -> next ds_write safe
    }

    float inv4[4];
#pragma unroll
    for (int i = 0; i < 4; ++i) {
      float v = rs4[i];
      v += __shfl_xor(v, 1, 64);
      v += __shfl_xor(v, 2, 64);
      v += __shfl_xor(v, 4, 64);
      v += __shfl_xor(v, 8, 64);
      inv4[i] = RCP(v);
    }
#pragma unroll
    for (int n = 0; n < 8; ++n)
#pragma unroll
      for (int i = 0; i < 4; ++i)
        O[(size_t)(t0 + li4 + i) * DMODEL + h * HDIM + n * 16 + lr] =
            f2b(oacc[n][i] * inv4[i]);
  }
}

// ---------- launch ----------

extern "C" void kernel_launch(void* const* d_in, const int* in_sizes, int n_in,
                              void* d_out, int out_size, void* d_ws, size_t ws_size,
                              hipStream_t stream) {
  const int*   pos  = (const int*)d_in[0];
  const float* hid  = (const float*)d_in[1];
  const float* wqkv = (const float*)d_in[2];
  const float* wo   = (const float*)d_in[3];
  float* out = (float*)d_out;
  char* ws = (char*)d_ws;

  const size_t O_XB   = 0;                         // Xb bf16 [2048][6144]; later attn_out
  const size_t O_WQT  = 25165824;                  // Wqkv^T bf16 [8192][6144]; later Q/K/Vt
  const size_t O_WOT  = 125829120;                 // Wo^T bf16 [6144][6144]
  const size_t O_QKV  = 201326592;                 // QKV bf16 [2048][8192]
  const size_t O_TRIG = 268435456;                 // cos/sin f32 [2048][64] each

  unsigned short* Xb  = (unsigned short*)(ws + O_XB);
  unsigned short* Wqt = (unsigned short*)(ws + O_WQT);
  unsigned short* Wot = (unsigned short*)(ws + O_WOT);
  unsigned short* QKVb = (unsigned short*)(ws + O_QKV);
  float* CS  = (float*)(ws + O_TRIG);
  float* SN  = CS + TSEQ * 64;
  unsigned short* Qr = Wqt;                                  // [48][2048][128]
  unsigned short* Kr = Wqt + (size_t)NHEADS * TSEQ * HDIM;   // [8][2048][128]
  unsigned short* Vt = Kr + (size_t)NKVH * TSEQ * HDIM;      // [8][128][2048]
  unsigned short* AO = Xb;                                   // attn_out bf16 [2048][6144]

  hipFuncSetAttribute((const void*)k_gemm8<unsigned short>,
                      hipFuncAttributeMaxDynamicSharedMemorySize, 131072);
  hipFuncSetAttribute((const void*)k_gemm8<float>,
                      hipFuncAttributeMaxDynamicSharedMemorySize, 131072);

  k_cvt<<<(TSEQ * DMODEL) / (256 * 8), 256, 0, stream>>>(hid, Xb, TSEQ * DMODEL);
  // Wqkv^T: in 6144x8192 -> out 8192x6144
  k_tr2<<<dim3(QKVC / 64, DMODEL / 64, 1), 256, 0, stream>>>(wqkv, QKVC, 0, Wqt, DMODEL, 0);
  // Wo^T: in 6144x6144 -> out 6144x6144
  k_tr2<<<dim3(DMODEL / 64, DMODEL / 64, 1), 256, 0, stream>>>(wo, DMODEL, 0, Wot, DMODEL, 0);
  k_trig<<<TSEQ, 64, 0, stream>>>(pos, CS, SN);

  k_gemm8<unsigned short><<<(TSEQ / 256) * (QKVC / 256), 512, 131072, stream>>>(
      Xb, Wqt, QKVb, TSEQ, QKVC, DMODEL);
  k_rope<<<TSEQ, 256, 0, stream>>>(QKVb, CS, SN, Qr, Kr);
  // Vt: per head z, in QKVb[t][7168 + z*128 + d] (2048x128 bf16) -> Vt[z][d][t]
  k_tr2b<<<dim3(HDIM / 64, TSEQ / 64, NKVH), 256, 0, stream>>>(
      QKVb + (size_t)(DMODEL + NKVH * HDIM), QKVC, HDIM,
      Vt, TSEQ, (size_t)HDIM * TSEQ);
  k_attn2<<<768, 256, 0, stream>>>(Qr, Kr, Vt, AO);
  k_gemm8<float><<<(TSEQ / 256) * (DMODEL / 256), 512, 131072, stream>>>(
      AO, Wot, out, TSEQ, DMODEL, DMODEL);
}

// Round 12
// 541.940 us; speedup vs baseline: 1.2497x; 1.2497x over previous
//
#include <hip/hip_runtime.h>
#include <hip/hip_bf16.h>
#include <stdint.h>

#define TSEQ   2048
#define DMODEL 6144
#define NHEADS 48
#define NKVH   8
#define HDIM   128
#define QKVC   8192   // (48 + 2*8) * 128
#define GRP    6      // NHEADS / NKVH

typedef __attribute__((ext_vector_type(8))) short short8;
typedef __attribute__((ext_vector_type(4))) float f32x4;

// ---------- helpers ----------

__device__ __forceinline__ unsigned short f2b(float f) {
  union { float f; unsigned int u; } v; v.f = f;
  unsigned int u = v.u;
  unsigned int r = (u + 0x7FFFu + ((u >> 16) & 1u)) >> 16;  // RNE
  return (unsigned short)r;
}

__device__ __forceinline__ float b2f(unsigned short s) {
  union { unsigned int u; float f; } v; v.u = ((unsigned int)s) << 16;
  return v.f;
}

#if __has_builtin(__builtin_amdgcn_exp2f)
#define EXP2(x) __builtin_amdgcn_exp2f(x)
#else
#define EXP2(x) exp2f(x)
#endif
#if __has_builtin(__builtin_amdgcn_rcpf)
#define RCP(x) __builtin_amdgcn_rcpf(x)
#else
#define RCP(x) (1.0f / (x))
#endif

typedef const __attribute__((address_space(1))) void* as1_cvp;
typedef __attribute__((address_space(3))) void* as3_vp;

__device__ __forceinline__ void gload_lds16(const void* g, void* l) {
  // LDS dest is wave-uniform base + lane*16 (layouts below are linear in tid)
  __builtin_amdgcn_global_load_lds(
      (as1_cvp)(uintptr_t)g,
      (as3_vp)(unsigned int)(uintptr_t)l, 16, 0, 0);
}

#define LGKMC(n) do { asm volatile("s_waitcnt lgkmcnt(" #n ")" ::: "memory"); \
                      __builtin_amdgcn_sched_barrier(0); } while (0)
#define VMC(n) do { asm volatile("s_waitcnt vmcnt(" #n ")" ::: "memory"); \
                    __builtin_amdgcn_sched_barrier(0); } while (0)
#define BARR  do { asm volatile("s_barrier" ::: "memory"); } while (0)

// ---------- prep kernels ----------

__global__ __launch_bounds__(256) void k_cvt(const float* __restrict__ in,
                                             unsigned short* __restrict__ outp, int n) {
  int i = (blockIdx.x * 256 + threadIdx.x) * 8;
  if (i + 7 < n) {
    float4 va = *(const float4*)(in + i);
    float4 vb = *(const float4*)(in + i + 4);
    union { unsigned short s[8]; uint4 u; } o;
    o.s[0] = f2b(va.x); o.s[1] = f2b(va.y); o.s[2] = f2b(va.z); o.s[3] = f2b(va.w);
    o.s[4] = f2b(vb.x); o.s[5] = f2b(vb.y); o.s[6] = f2b(vb.z); o.s[7] = f2b(vb.w);
    *(uint4*)(outp + i) = o.u;
  }
}

// f32 -> bf16 64x64 tile transpose: out[c][r] = in[r][c]
__global__ __launch_bounds__(256) void k_tr2(const float* __restrict__ in, long istr, long zin,
                                             unsigned short* __restrict__ out, long ostr, long zout) {
  __shared__ unsigned short tile[64][68];
  const int tid = threadIdx.x;
  const int br = blockIdx.y * 64;      // input row base
  const int bc = blockIdx.x * 64;      // input col base
  in  += (size_t)blockIdx.z * zin;
  out += (size_t)blockIdx.z * zout;
  const int row = tid >> 4;            // 0..15
  const int c4  = (tid & 15) * 4;
#pragma unroll
  for (int p = 0; p < 4; ++p) {
    const int r = p * 16 + row;
    float4 v = *(const float4*)(in + (size_t)(br + r) * istr + bc + c4);
    tile[r][c4 + 0] = f2b(v.x);
    tile[r][c4 + 1] = f2b(v.y);
    tile[r][c4 + 2] = f2b(v.z);
    tile[r][c4 + 3] = f2b(v.w);
  }
  __syncthreads();
#pragma unroll
  for (int p = 0; p < 4; ++p) {
    const int r = p * 16 + row;        // out row (= input col index)
    union { unsigned short s[4]; uint2 u; } o;
    o.s[0] = tile[c4 + 0][r];
    o.s[1] = tile[c4 + 1][r];
    o.s[2] = tile[c4 + 2][r];
    o.s[3] = tile[c4 + 3][r];
    *(uint2*)(out + (size_t)(bc + r) * ostr + br + c4) = o.u;
  }
}

// bf16 -> bf16 64x64 tile transpose: out[c][r] = in[r][c]
__global__ __launch_bounds__(256) void k_tr2b(const unsigned short* __restrict__ in, long istr, long zin,
                                              unsigned short* __restrict__ out, long ostr, long zout) {
  __shared__ unsigned short tile[64][68];
  const int tid = threadIdx.x;
  const int br = blockIdx.y * 64;
  const int bc = blockIdx.x * 64;
  in  += (size_t)blockIdx.z * zin;
  out += (size_t)blockIdx.z * zout;
  const int row = tid >> 4;            // 0..15
  const int c4  = (tid & 15) * 4;
#pragma unroll
  for (int p = 0; p < 4; ++p) {
    const int r = p * 16 + row;
    union { unsigned short s[4]; uint2 u; } v;
    v.u = *(const uint2*)(in + (size_t)(br + r) * istr + bc + c4);
    tile[r][c4 + 0] = v.s[0];
    tile[r][c4 + 1] = v.s[1];
    tile[r][c4 + 2] = v.s[2];
    tile[r][c4 + 3] = v.s[3];
  }
  __syncthreads();
#pragma unroll
  for (int p = 0; p < 4; ++p) {
    const int r = p * 16 + row;
    union { unsigned short s[4]; uint2 u; } o;
    o.s[0] = tile[c4 + 0][r];
    o.s[1] = tile[c4 + 1][r];
    o.s[2] = tile[c4 + 2][r];
    o.s[3] = tile[c4 + 3][r];
    *(uint2*)(out + (size_t)(bc + r) * ostr + br + c4) = o.u;
  }
}

__global__ void k_trig(const int* __restrict__ pos, float* __restrict__ cs,
                       float* __restrict__ sn) {
  int t = blockIdx.x, i = threadIdx.x;  // block=64
  float p = (float)pos[t];
  float inv = EXP2(-(float)(2 * i) * (1.0f / 128.0f) * 13.287712379549449f);
  float f = p * inv;
  cs[t * 64 + i] = cosf(f);
  sn[t * 64 + i] = sinf(f);
}

// ---------- GEMM 256x256x64: round-9 schedule (best verified: 179us, 0 conflicts) ----------
// A[M][K] bf16 row-major, Bt[N][K] bf16, C[M][N] f32 or bf16.
// 512 thr = 8 waves (2M x 4N); per-wave out 128x64 = acc[8][4] f32x4.
// LDS (dynamic 128 KiB): buf b at b*65536: A 256 rows x 128 B (XOR-swizzled
// byte^=(row&7)<<4), B at +32768 same.
// Per tile t (buf cur=t&1): issue ALL 24 ds_reads up-front (a0,b0 | b1 | a1),
// STAGE_B(t+1) interleaved; consume with counted lgkmcnt; 2 barriers/tile:
//   lgkm(12) MFMA(0,0); lgkm(8) MFMA(0,1); lgkm(0) MFMA(1,0);
//   BARR; STAGE_A(t+2,cur); MFMA(1,1); vmcnt(4); BARR
// Ledger: vmcnt(4) leaves A(t+2) in flight; A(t+1), B(t+1) landed. lgkm(0)
// precedes mid-BARR so all reads of buf cur drain before STAGE_A overwrites.

#define READ_A(mh, aa) do { \
  _Pragma("unroll") for (int m = 0; m < 4; ++m) \
  _Pragma("unroll") for (int ks = 0; ks < 2; ++ks) \
    aa[m][ks] = *(const short8*)(LA + (wm * 128 + (mh) * 64 + m * 16 + lr) * 128 \
                                 + ((ks * 64 + lkb) ^ lsw)); } while (0)

#define READ_B(nh, bb) do { \
  _Pragma("unroll") for (int n2 = 0; n2 < 2; ++n2) \
  _Pragma("unroll") for (int ks = 0; ks < 2; ++ks) \
    bb[n2][ks] = *(const short8*)(LB + (wn * 64 + (nh) * 32 + n2 * 16 + lr) * 128 \
                                  + ((ks * 64 + lkb) ^ lsw)); } while (0)

#define CLUSTER(mh, nh, aa, bb) do { \
  __builtin_amdgcn_s_setprio(1); \
  _Pragma("unroll") for (int m = 0; m < 4; ++m) \
  _Pragma("unroll") for (int n2 = 0; n2 < 2; ++n2) \
  _Pragma("unroll") for (int ks = 0; ks < 2; ++ks) \
    acc[(mh) * 4 + m][(nh) * 2 + n2] = __builtin_amdgcn_mfma_f32_16x16x32_bf16( \
        aa[m][ks], bb[n2][ks], acc[(mh) * 4 + m][(nh) * 2 + n2], 0, 0, 0); \
  __builtin_amdgcn_s_setprio(0); } while (0)

#define STAGE_A(kt, bb) do { \
  _Pragma("unroll") for (int i = 0; i < 4; ++i) \
    gload_lds16(Asrc + (size_t)(kt) * 64 + (size_t)i * 64 * K, \
                lds + (bb) * 65536 + F + i * 8192); } while (0)

#define STAGE_B(kt, bb) do { \
  _Pragma("unroll") for (int i = 0; i < 4; ++i) \
    gload_lds16(Bsrc + (size_t)(kt) * 64 + (size_t)i * 64 * K, \
                lds + (bb) * 65536 + 32768 + F + i * 8192); } while (0)

template <typename OutT>
__global__ __launch_bounds__(512, 2) void k_gemm8(const unsigned short* __restrict__ A,
                                                  const unsigned short* __restrict__ Bt,
                                                  OutT* __restrict__ C,
                                                  int M, int N, int K) {
  extern __shared__ __align__(16) unsigned char lds[];
  const int tid  = threadIdx.x;
  const int lane = tid & 63;
  const int wave = tid >> 6;
  const int wm = wave >> 2;           // 0..1
  const int wn = wave & 3;            // 0..3
  const int lr  = lane & 15;
  const int lkb = (lane >> 4) * 16;
  const int li4 = (lane >> 4) * 4;
  const int lsw = (lane & 7) << 4;    // read-side swizzle const

  // XCD n-stripe mapping: xcd = lin&7 owns n-cols [xcd*Cx, (xcd+1)*Cx)
  const int mt = M >> 8;
  const int nt = N >> 8;
  const int Cx = nt >> 3;
  const int lin = blockIdx.x;
  const int xcd = lin & 7;
  const int r   = lin >> 3;
  const int m0  = (r % mt) << 8;
  const int n0  = (xcd * Cx + r / mt) << 8;

  // staging: thread's 16B chunk; row advances 64 per load index
  const int F   = tid * 16;
  const int r0  = F >> 7;
  const int cbs = (F & 127) ^ ((r0 & 7) << 4);   // pre-swizzled source col
  const unsigned short* Asrc = A  + (size_t)(m0 + r0) * K + (cbs >> 1);
  const unsigned short* Bsrc = Bt + (size_t)(n0 + r0) * K + (cbs >> 1);

  const int NT = K >> 6;

  f32x4 acc[8][4];
#pragma unroll
  for (int i = 0; i < 8; ++i)
#pragma unroll
    for (int j = 0; j < 4; ++j) acc[i][j] = (f32x4){0.f, 0.f, 0.f, 0.f};

  // prologue: A(0),B(0)->buf0, A(1)->buf1; wait first 8, keep A(1) flying
  STAGE_A(0, 0);
  STAGE_B(0, 0);
  STAGE_A(1, 1);
  VMC(4);
  BARR;

  for (int t = 0; t < NT; ++t) {
    const int cur = t & 1;
    const unsigned char* LA = lds + cur * 65536;
    const unsigned char* LB = LA + 32768;
    short8 a0[4][2], a1[4][2], b0[2][2], b1[2][2];

    // issue all reads up-front; stage B(t+1) interleaved
    READ_A(0, a0);                       // 8  (lgkm 8)
    READ_B(0, b0);                       // 4  (lgkm 12)
    if (t + 1 < NT) STAGE_B(t + 1, cur ^ 1);
    READ_B(1, b1);                       // 4  (lgkm 16)
    READ_A(1, a1);                       // 8  (lgkm 24)

    LGKMC(12);                           // a0,b0 landed
    CLUSTER(0, 0, a0, b0);
    LGKMC(8);                            // b1 landed
    CLUSTER(0, 1, a0, b1);
    LGKMC(0);                            // a1 landed (all reads drained)
    CLUSTER(1, 0, a1, b0);
    BARR;                                // all waves drained -> safe to overwrite A(cur)
    if (t + 2 < NT) STAGE_A(t + 2, cur);
    CLUSTER(1, 1, a1, b1);               // register-only, overlaps stage
    if (t + 2 < NT) { VMC(4); } else { VMC(0); }
    BARR;
  }

#pragma unroll
  for (int mh = 0; mh < 2; ++mh)
#pragma unroll
    for (int m = 0; m < 4; ++m)
#pragma unroll
      for (int nh = 0; nh < 2; ++nh)
#pragma unroll
        for (int n2 = 0; n2 < 2; ++n2)
#pragma unroll
          for (int i = 0; i < 4; ++i) {
            int row = m0 + wm * 128 + mh * 64 + m * 16 + li4 + i;
            int col = n0 + wn * 64 + nh * 32 + n2 * 16 + lr;
            float v = acc[mh * 4 + m][nh * 2 + n2][i];
            if constexpr (sizeof(OutT) == 2)
              C[(size_t)row * N + col] = (OutT)f2b(v);
            else
              C[(size_t)row * N + col] = (OutT)v;
          }
}

// ---------- RoPE + split: QKV bf16 [T][8192] -> Q[h][t][d], K[h][t][d] (bf16) ----------

__global__ __launch_bounds__(256) void k_rope(const unsigned short* __restrict__ qkv,
                                              const float* __restrict__ cs,
                                              const float* __restrict__ sn,
                                              unsigned short* __restrict__ Q,
                                              unsigned short* __restrict__ K) {
  const int t = blockIdx.x;
  const int tid = threadIdx.x;
  const unsigned short* row = qkv + (size_t)t * QKVC;
  const float* c = cs + t * 64;
  const float* s = sn + t * 64;
  for (int p = tid; p < 56 * 16; p += 256) {
    const int h = p >> 4, q4 = (p & 15) * 4;
    const unsigned short* src = row + h * 128;
    union { unsigned short sh[4]; uint2 u; } x1u, x2u;
    x1u.u = *(const uint2*)(src + q4);
    x2u.u = *(const uint2*)(src + 64 + q4);
    float4 cc = *(const float4*)(c + q4);
    float4 ss = *(const float4*)(s + q4);
    unsigned short* dst = (h < NHEADS)
        ? Q + ((size_t)h * TSEQ + t) * HDIM
        : K + ((size_t)(h - NHEADS) * TSEQ + t) * HDIM;
    float x10 = b2f(x1u.sh[0]), x11 = b2f(x1u.sh[1]),
          x12 = b2f(x1u.sh[2]), x13 = b2f(x1u.sh[3]);
    float x20 = b2f(x2u.sh[0]), x21 = b2f(x2u.sh[1]),
          x22 = b2f(x2u.sh[2]), x23 = b2f(x2u.sh[3]);
    union { unsigned short sh[4]; uint2 u; } o1, o2;
    o1.sh[0] = f2b(x10 * cc.x - x20 * ss.x);
    o1.sh[1] = f2b(x11 * cc.y - x21 * ss.y);
    o1.sh[2] = f2b(x12 * cc.z - x22 * ss.z);
    o1.sh[3] = f2b(x13 * cc.w - x23 * ss.w);
    o2.sh[0] = f2b(x20 * cc.x + x10 * ss.x);
    o2.sh[1] = f2b(x21 * cc.y + x11 * ss.y);
    o2.sh[2] = f2b(x22 * cc.z + x12 * ss.z);
    o2.sh[3] = f2b(x23 * cc.w + x13 * ss.w);
    *(uint2*)(dst + q4) = o1.u;
    *(uint2*)(dst + 64 + q4) = o2.u;
  }
}

// ---------- attention: balanced pairs + DOUBLE-BUFFERED gload_lds pipeline ----------
// Back to global_load_lds (linear LDS dest + pre-swizzled global source; the
// verified rounds-2..10 pattern), but K/V LDS is double-buffered: stage(st+1)
// into buf^1 is issued BEFORE compute(st), and drained by an explicit VMC(0)
// only AFTER the ~600-cyc compute phase -> HBM/L2 latency hides under compute
// instead of being serially drained at each step's barrier (round-11 lesson:
// __syncthreads' implicit vmcnt(0) defeats async staging; use raw s_barrier
// + explicit counted waits).
// Safety: buf^1's last readers ran in step st-1, whose reads completed before
// the end-of-step barrier of st-1; stage(st+1) is issued after that barrier.
// VMC(0)+BARR at end of st ensure buf^1 is fully landed before st+1 reads it.
// LDS: 2*(16K K + 16K V) + 8K P = 72 KB -> 2 blocks/CU.

__global__ __launch_bounds__(256, 2) void k_attn3(const unsigned short* __restrict__ Q,
                                                  const unsigned short* __restrict__ K,
                                                  const unsigned short* __restrict__ V,  // Vt[h][d][t]
                                                  unsigned short* __restrict__ O) {
  __shared__ __align__(16) unsigned char KsB[2][16384];   // 64 s-rows x 256 B (swizzled)
  __shared__ __align__(16) unsigned char VsB[2][16384];   // 128 d-rows x 128 B (swizzled)
  __shared__ __align__(16) unsigned char PsB[4][2048];    // per-wave 16 q-rows x 128 B (swizzled)

  const int lin = blockIdx.x;
  const int g   = lin & 7;            // kv head == XCD hint
  const int rr  = lin >> 3;           // 0..95
  const int hg  = rr % 6;
  const int pr  = rr / 6;             // 0..15
  const int h   = g * 6 + hg;
  const int tid = threadIdx.x, wave = tid >> 6, lane = tid & 63;
  const int lr = lane & 15, lk = (lane >> 4) * 8, li4 = (lane >> 4) * 4;
  const unsigned short* Qh = Q + (size_t)h * (TSEQ * HDIM);
  const unsigned char*  Kb = (const unsigned char*)(K + (size_t)g * (TSEQ * HDIM));
  const unsigned char*  Vb = (const unsigned char*)(V + (size_t)g * (TSEQ * HDIM));
  unsigned char* Pw = PsB[wave];

#define STAGE_KV(st_, b_) do { \
  const int s_ = (st_) * 64; \
  _Pragma("unroll") for (int c = 0; c < 4; ++c) { \
    const int FF = tid * 16 + c * 4096; \
    const int krow = FF >> 8; \
    const int kcol = (FF & 255) ^ ((krow & 7) << 4); \
    gload_lds16(Kb + (size_t)(s_ + krow) * 256 + kcol, KsB[b_] + FF); \
    const int vrow = FF >> 7; \
    const int vcol = (FF & 127) ^ ((vrow & 7) << 4); \
    gload_lds16(Vb + (size_t)vrow * (TSEQ * 2) + (size_t)s_ * 2 + vcol, VsB[b_] + FF); \
  } } while (0)

  for (int half = 0; half < 2; ++half) {
    const int j  = half ? (31 - pr) : pr;     // q-tile index (64 rows)
    const int t0 = j * 64 + wave * 16;        // this wave's 16 rows
    const int nst = j + 1;

    short8 qf[4];
#pragma unroll
    for (int ks = 0; ks < 4; ++ks)
      qf[ks] = *(const short8*)(Qh + (size_t)(t0 + lr) * HDIM + ks * 32 + lk);

    f32x4 oacc[8];
#pragma unroll
    for (int n = 0; n < 8; ++n) oacc[n] = (f32x4){0.f, 0.f, 0.f, 0.f};
    float rs4[4] = {0.f, 0.f, 0.f, 0.f};

    // prologue: stage st=0 into buf 0, drain, sync
    STAGE_KV(0, 0);
    VMC(0);
    BARR;

    for (int st = 0; st < nst; ++st) {
      const int cur = st & 1;
      // issue next step's staging BEFORE compute; lands during compute
      if (st + 1 < nst) STAGE_KV(st + 1, cur ^ 1);

      const unsigned char* Ks = KsB[cur];
      const unsigned char* Vs = VsB[cur];
      const int s0 = st * 64;
      f32x4 sacc[4];
#pragma unroll
      for (int n = 0; n < 4; ++n) sacc[n] = (f32x4){0.f, 0.f, 0.f, 0.f};
#pragma unroll
      for (int ks = 0; ks < 4; ++ks) {
        short8 kf[4];
#pragma unroll
        for (int n = 0; n < 4; ++n) {
          const int row = n * 16 + lr;
          kf[n] = *(const short8*)(Ks + row * 256 + ((ks * 64 + lk * 2) ^ ((row & 7) << 4)));
        }
#pragma unroll
        for (int n = 0; n < 4; ++n)
          sacc[n] = __builtin_amdgcn_mfma_f32_16x16x32_bf16(qf[ks], kf[n], sacc[n], 0, 0, 0);
      }

      const bool lastst = (st == nst - 1);
#pragma unroll
      for (int n = 0; n < 4; ++n)
#pragma unroll
        for (int i = 0; i < 4; ++i) {
          float sv = sacc[n][i] * 0.08838834764831845f;   // 1/sqrt(128)
          float e = EXP2(sv * 0.09617966939259757f);       // e^(s/15)
          float p = EXP2(-86.5617024533378f * RCP(e + 1.0f));
          if (lastst && (s0 + n * 16 + lr > t0 + li4 + i)) p = 0.f;
          rs4[i] += p;
          const int prow = li4 + i;
          *(unsigned short*)(Pw + prow * 128 +
              (((n * 16 + lr) * 2) ^ ((prow & 7) << 4))) = f2b(p);
        }

#pragma unroll
      for (int ks2 = 0; ks2 < 2; ++ks2) {
        short8 pf = *(const short8*)(Pw + lr * 128 +
                         (((ks2 * 32 + lk) * 2) ^ ((lr & 7) << 4)));
        short8 vf[8];
#pragma unroll
        for (int n = 0; n < 8; ++n) {
          const int row = n * 16 + lr;
          vf[n] = *(const short8*)(Vs + row * 128 + ((ks2 * 64 + lk * 2) ^ ((row & 7) << 4)));
        }
#pragma unroll
        for (int n = 0; n < 8; ++n)
          oacc[n] = __builtin_amdgcn_mfma_f32_16x16x32_bf16(pf, vf[n], oacc[n], 0, 0, 0);
      }

      // drain next-step staging (latency hidden under the compute above),
      // then sync so (a) buf^1 is ready for st+1 and (b) all waves' reads of
      // buf cur are done before st+1 stages into it.
      VMC(0);
      BARR;
    }

    float inv4[4];
#pragma unroll
    for (int i = 0; i < 4; ++i) {
      float v = rs4[i];
      v += __shfl_xor(v, 1, 64);
      v += __shfl_xor(v, 2, 64);
      v += __shfl_xor(v, 4, 64);
      v += __shfl_xor(v, 8, 64);
      inv4[i] = RCP(v);
    }
#pragma unroll
    for (int n = 0; n < 8; ++n)
#pragma unroll
      for (int i = 0; i < 4; ++i)
        O[(size_t)(t0 + li4 + i) * DMODEL + h * HDIM + n * 16 + lr] =
            f2b(oacc[n][i] * inv4[i]);
    BARR;   // protect LDS before next half re-stages buf 0
  }
#undef STAGE_KV
}

// ---------- launch ----------

extern "C" void kernel_launch(void* const* d_in, const int* in_sizes, int n_in,
                              void* d_out, int out_size, void* d_ws, size_t ws_size,
                              hipStream_t stream) {
  const int*   pos  = (const int*)d_in[0];
  const float* hid  = (const float*)d_in[1];
  const float* wqkv = (const float*)d_in[2];
  const float* wo   = (const float*)d_in[3];
  float* out = (float*)d_out;
  char* ws = (char*)d_ws;

  const size_t O_XB   = 0;                         // Xb bf16 [2048][6144]; later attn_out
  const size_t O_WQT  = 25165824;                  // Wqkv^T bf16 [8192][6144]; later Q/K/Vt
  const size_t O_WOT  = 125829120;                 // Wo^T bf16 [6144][6144]
  const size_t O_QKV  = 201326592;                 // QKV bf16 [2048][8192]
  const size_t O_TRIG = 268435456;                 // cos/sin f32 [2048][64] each

  unsigned short* Xb  = (unsigned short*)(ws + O_XB);
  unsigned short* Wqt = (unsigned short*)(ws + O_WQT);
  unsigned short* Wot = (unsigned short*)(ws + O_WOT);
  unsigned short* QKVb = (unsigned short*)(ws + O_QKV);
  float* CS  = (float*)(ws + O_TRIG);
  float* SN  = CS + TSEQ * 64;
  unsigned short* Qr = Wqt;                                  // [48][2048][128]
  unsigned short* Kr = Wqt + (size_t)NHEADS * TSEQ * HDIM;   // [8][2048][128]
  unsigned short* Vt = Kr + (size_t)NKVH * TSEQ * HDIM;      // [8][128][2048]
  unsigned short* AO = Xb;                                   // attn_out bf16 [2048][6144]

  hipFuncSetAttribute((const void*)k_gemm8<unsigned short>,
                      hipFuncAttributeMaxDynamicSharedMemorySize, 131072);
  hipFuncSetAttribute((const void*)k_gemm8<float>,
                      hipFuncAttributeMaxDynamicSharedMemorySize, 131072);

  k_cvt<<<(TSEQ * DMODEL) / (256 * 8), 256, 0, stream>>>(hid, Xb, TSEQ * DMODEL);
  // Wqkv^T: in 6144x8192 -> out 8192x6144
  k_tr2<<<dim3(QKVC / 64, DMODEL / 64, 1), 256, 0, stream>>>(wqkv, QKVC, 0, Wqt, DMODEL, 0);
  // Wo^T: in 6144x6144 -> out 6144x6144
  k_tr2<<<dim3(DMODEL / 64, DMODEL / 64, 1), 256, 0, stream>>>(wo, DMODEL, 0, Wot, DMODEL, 0);
  k_trig<<<TSEQ, 64, 0, stream>>>(pos, CS, SN);

  k_gemm8<unsigned short><<<(TSEQ / 256) * (QKVC / 256), 512, 131072, stream>>>(
      Xb, Wqt, QKVb, TSEQ, QKVC, DMODEL);
  k_rope<<<TSEQ, 256, 0, stream>>>(QKVb, CS, SN, Qr, Kr);
  // Vt: per head z, in QKVb[t][7168 + z*128 + d] (2048x128 bf16) -> Vt[z][d][t]
  k_tr2b<<<dim3(HDIM / 64, TSEQ / 64, NKVH), 256, 0, stream>>>(
      QKVb + (size_t)(DMODEL + NKVH * HDIM), QKVC, HDIM,
      Vt, TSEQ, (size_t)HDIM * TSEQ);
  k_attn3<<<768, 256, 0, stream>>>(Qr, Kr, Vt, AO);
  k_gemm8<float><<<(TSEQ / 256) * (DMODEL / 256), 512, 131072, stream>>>(
      AO, Wot, out, TSEQ, DMODEL, DMODEL);
}

// Round 14
// 524.889 us; speedup vs baseline: 1.2903x; 1.0325x over previous
//
#include <hip/hip_runtime.h>
#include <hip/hip_bf16.h>
#include <stdint.h>

#define TSEQ   2048
#define DMODEL 6144
#define NHEADS 48
#define NKVH   8
#define HDIM   128
#define QKVC   8192   // (48 + 2*8) * 128
#define GRP    6      // NHEADS / NKVH

typedef __attribute__((ext_vector_type(8))) short short8;
typedef __attribute__((ext_vector_type(4))) float f32x4;

// ---------- helpers ----------

__device__ __forceinline__ unsigned short f2b(float f) {
  union { float f; unsigned int u; } v; v.f = f;
  unsigned int u = v.u;
  unsigned int r = (u + 0x7FFFu + ((u >> 16) & 1u)) >> 16;  // RNE
  return (unsigned short)r;
}

__device__ __forceinline__ float b2f(unsigned short s) {
  union { unsigned int u; float f; } v; v.u = ((unsigned int)s) << 16;
  return v.f;
}

#if __has_builtin(__builtin_amdgcn_exp2f)
#define EXP2(x) __builtin_amdgcn_exp2f(x)
#else
#define EXP2(x) exp2f(x)
#endif
#if __has_builtin(__builtin_amdgcn_rcpf)
#define RCP(x) __builtin_amdgcn_rcpf(x)
#else
#define RCP(x) (1.0f / (x))
#endif

typedef const __attribute__((address_space(1))) void* as1_cvp;
typedef __attribute__((address_space(3))) void* as3_vp;

__device__ __forceinline__ void gload_lds16(const void* g, void* l) {
  // LDS dest is wave-uniform base + lane*16 (layouts below are linear in tid)
  __builtin_amdgcn_global_load_lds(
      (as1_cvp)(uintptr_t)g,
      (as3_vp)(unsigned int)(uintptr_t)l, 16, 0, 0);
}

#define LGKMC(n) do { asm volatile("s_waitcnt lgkmcnt(" #n ")" ::: "memory"); \
                      __builtin_amdgcn_sched_barrier(0); } while (0)
#define VMC(n) do { asm volatile("s_waitcnt vmcnt(" #n ")" ::: "memory"); \
                    __builtin_amdgcn_sched_barrier(0); } while (0)
#define BARR  do { asm volatile("s_barrier" ::: "memory"); } while (0)

// ---------- prep kernels ----------

__global__ __launch_bounds__(256) void k_cvt(const float* __restrict__ in,
                                             unsigned short* __restrict__ outp, int n) {
  int i = (blockIdx.x * 256 + threadIdx.x) * 8;
  if (i + 7 < n) {
    float4 va = *(const float4*)(in + i);
    float4 vb = *(const float4*)(in + i + 4);
    union { unsigned short s[8]; uint4 u; } o;
    o.s[0] = f2b(va.x); o.s[1] = f2b(va.y); o.s[2] = f2b(va.z); o.s[3] = f2b(va.w);
    o.s[4] = f2b(vb.x); o.s[5] = f2b(vb.y); o.s[6] = f2b(vb.z); o.s[7] = f2b(vb.w);
    *(uint4*)(outp + i) = o.u;
  }
}

// f32 -> bf16 64x64 tile transpose: out[c][r] = in[r][c]
__global__ __launch_bounds__(256) void k_tr2(const float* __restrict__ in, long istr, long zin,
                                             unsigned short* __restrict__ out, long ostr, long zout) {
  __shared__ unsigned short tile[64][68];
  const int tid = threadIdx.x;
  const int br = blockIdx.y * 64;      // input row base
  const int bc = blockIdx.x * 64;      // input col base
  in  += (size_t)blockIdx.z * zin;
  out += (size_t)blockIdx.z * zout;
  const int row = tid >> 4;            // 0..15
  const int c4  = (tid & 15) * 4;
#pragma unroll
  for (int p = 0; p < 4; ++p) {
    const int r = p * 16 + row;
    float4 v = *(const float4*)(in + (size_t)(br + r) * istr + bc + c4);
    tile[r][c4 + 0] = f2b(v.x);
    tile[r][c4 + 1] = f2b(v.y);
    tile[r][c4 + 2] = f2b(v.z);
    tile[r][c4 + 3] = f2b(v.w);
  }
  __syncthreads();
#pragma unroll
  for (int p = 0; p < 4; ++p) {
    const int r = p * 16 + row;        // out row (= input col index)
    union { unsigned short s[4]; uint2 u; } o;
    o.s[0] = tile[c4 + 0][r];
    o.s[1] = tile[c4 + 1][r];
    o.s[2] = tile[c4 + 2][r];
    o.s[3] = tile[c4 + 3][r];
    *(uint2*)(out + (size_t)(bc + r) * ostr + br + c4) = o.u;
  }
}

// bf16 -> bf16 64x64 tile transpose: out[c][r] = in[r][c]
__global__ __launch_bounds__(256) void k_tr2b(const unsigned short* __restrict__ in, long istr, long zin,
                                              unsigned short* __restrict__ out, long ostr, long zout) {
  __shared__ unsigned short tile[64][68];
  const int tid = threadIdx.x;
  const int br = blockIdx.y * 64;
  const int bc = blockIdx.x * 64;
  in  += (size_t)blockIdx.z * zin;
  out += (size_t)blockIdx.z * zout;
  const int row = tid >> 4;            // 0..15
  const int c4  = (tid & 15) * 4;
#pragma unroll
  for (int p = 0; p < 4; ++p) {
    const int r = p * 16 + row;
    union { unsigned short s[4]; uint2 u; } v;
    v.u = *(const uint2*)(in + (size_t)(br + r) * istr + bc + c4);
    tile[r][c4 + 0] = v.s[0];
    tile[r][c4 + 1] = v.s[1];
    tile[r][c4 + 2] = v.s[2];
    tile[r][c4 + 3] = v.s[3];
  }
  __syncthreads();
#pragma unroll
  for (int p = 0; p < 4; ++p) {
    const int r = p * 16 + row;
    union { unsigned short s[4]; uint2 u; } o;
    o.s[0] = tile[c4 + 0][r];
    o.s[1] = tile[c4 + 1][r];
    o.s[2] = tile[c4 + 2][r];
    o.s[3] = tile[c4 + 3][r];
    *(uint2*)(out + (size_t)(bc + r) * ostr + br + c4) = o.u;
  }
}

__global__ void k_trig(const int* __restrict__ pos, float* __restrict__ cs,
                       float* __restrict__ sn) {
  int t = blockIdx.x, i = threadIdx.x;  // block=64
  float p = (float)pos[t];
  float inv = EXP2(-(float)(2 * i) * (1.0f / 128.0f) * 13.287712379549449f);
  float f = p * inv;
  cs[t * 64 + i] = cosf(f);
  sn[t * 64 + i] = sinf(f);
}

// ---------- GEMM 256 x (64*NH2) x 64: round-9 schedule, templated over NH2 ----------
// A[M][K] bf16 row-major, Bt[N][K] bf16, C[M][N] f32 or bf16.
// BN = 64*NH2 (NH2=4 -> 256, NH2=3 -> 192; GEMM2 uses 192 so grid = 8*32 =
// 256 blocks = exactly 1/CU instead of 192/256 with 64 CUs idle).
// 512 thr = 8 waves (2M x 4N); per-wave out 128 x 16*NH2 = acc[8][NH2].
// LDS: buffer stride BUFSZ = 32768 + NH2*8192  (ROUND-13 BUG: literal 57344
// made NH2=4's buffers overlap by 8KB -> absmax 158. NH2=4 -> 65536, the
// proven round-9 layout; NH2=3 -> 57344.)
// buf b at b*BUFSZ: A 256 rows x 128 B (XOR-swizzled byte^=(row&7)<<4),
// B (64*NH2 rows) at +32768.
// Per tile t (buf cur=t&1): issue reads a0(8) | b_lo | STAGE_B(t+1) | b_hi |
// a1(8); counted lgkm ladder; 2 barriers/tile. Wait literals valid for BOTH
// NH2 (lgkm totals 24/22: LGKMC(12) drains a0+b_lo, LGKMC(8) drains b_hi,
// LGKMC(0) drains a1; DS completes in-order). vmcnt: end-of-tile outstanding
// = B(t+1)=NH2 + A(t+2)=4 -> VMC(4) leaves exactly A(t+2), asserts {A,B}(t+1)
// landed. LGKMC(0) precedes mid-BARR so all reads of buf cur drain before
// STAGE_A overwrites it.

#define READ_A(mh, aa) do { \
  _Pragma("unroll") for (int m = 0; m < 4; ++m) \
  _Pragma("unroll") for (int ks = 0; ks < 2; ++ks) \
    aa[m][ks] = *(const short8*)(LA + (wm * 128 + (mh) * 64 + m * 16 + lr) * 128 \
                                 + ((ks * 64 + lkb) ^ lsw)); } while (0)

#define READ_BR(s, cnt, bb) do { \
  _Pragma("unroll") for (int n2 = (s); n2 < (s) + (cnt); ++n2) \
  _Pragma("unroll") for (int ks = 0; ks < 2; ++ks) \
    bb[n2][ks] = *(const short8*)(LB + (wn * (16 * NH2) + n2 * 16 + lr) * 128 \
                                  + ((ks * 64 + lkb) ^ lsw)); } while (0)

#define CLUSTER(mh, s, cnt, aa, bb) do { \
  __builtin_amdgcn_s_setprio(1); \
  _Pragma("unroll") for (int m = 0; m < 4; ++m) \
  _Pragma("unroll") for (int n2 = (s); n2 < (s) + (cnt); ++n2) \
  _Pragma("unroll") for (int ks = 0; ks < 2; ++ks) \
    acc[(mh) * 4 + m][n2] = __builtin_amdgcn_mfma_f32_16x16x32_bf16( \
        aa[m][ks], bb[n2][ks], acc[(mh) * 4 + m][n2], 0, 0, 0); \
  __builtin_amdgcn_s_setprio(0); } while (0)

#define STAGE_A(kt, bb) do { \
  _Pragma("unroll") for (int i = 0; i < 4; ++i) \
    gload_lds16(Asrc + (size_t)(kt) * 64 + (size_t)i * 64 * K, \
                lds + (bb) * BUFSZ + F + i * 8192); } while (0)

#define STAGE_B(kt, bb) do { \
  _Pragma("unroll") for (int i = 0; i < NH2; ++i) \
    gload_lds16(Bsrc + (size_t)(kt) * 64 + (size_t)i * 64 * K, \
                lds + (bb) * BUFSZ + 32768 + F + i * 8192); } while (0)

template <int NH2, typename OutT>
__global__ __launch_bounds__(512, 2) void k_gemm8(const unsigned short* __restrict__ A,
                                                  const unsigned short* __restrict__ Bt,
                                                  OutT* __restrict__ C,
                                                  int M, int N, int K) {
  extern __shared__ __align__(16) unsigned char lds[];
  constexpr int BN    = 64 * NH2;
  constexpr int NB0   = (NH2 == 4) ? 2 : 1;      // b_lo frag count
  constexpr int NB1   = NH2 - NB0;               // b_hi frag count
  constexpr int BUFSZ = 32768 + NH2 * 8192;      // per-buffer LDS stride
  const int tid  = threadIdx.x;
  const int lane = tid & 63;
  const int wave = tid >> 6;
  const int wm = wave >> 2;           // 0..1
  const int wn = wave & 3;            // 0..3
  const int lr  = lane & 15;
  const int lkb = (lane >> 4) * 16;
  const int li4 = (lane >> 4) * 4;
  const int lsw = (lane & 7) << 4;    // read-side swizzle const

  // XCD n-stripe mapping: xcd = lin&7 owns n-cols [xcd*Cx, (xcd+1)*Cx)
  const int mt = M >> 8;
  const int nt = N / BN;
  const int Cx = nt >> 3;
  const int lin = blockIdx.x;
  const int xcd = lin & 7;
  const int r   = lin >> 3;
  const int m0  = (r % mt) << 8;
  const int n0  = (xcd * Cx + r / mt) * BN;

  // staging: thread's 16B chunk; row advances 64 per load index
  const int F   = tid * 16;
  const int r0  = F >> 7;
  const int cbs = (F & 127) ^ ((r0 & 7) << 4);   // pre-swizzled source col
  const unsigned short* Asrc = A  + (size_t)(m0 + r0) * K + (cbs >> 1);
  const unsigned short* Bsrc = Bt + (size_t)(n0 + r0) * K + (cbs >> 1);

  const int NT = K >> 6;

  f32x4 acc[8][NH2];
#pragma unroll
  for (int i = 0; i < 8; ++i)
#pragma unroll
    for (int j = 0; j < NH2; ++j) acc[i][j] = (f32x4){0.f, 0.f, 0.f, 0.f};

  // prologue: A(0),B(0)->buf0, A(1)->buf1; VMC(4) leaves A(1) in flight
  STAGE_A(0, 0);
  STAGE_B(0, 0);
  STAGE_A(1, 1);
  VMC(4);
  BARR;

  for (int t = 0; t < NT; ++t) {
    const int cur = t & 1;
    const unsigned char* LA = lds + cur * BUFSZ;
    const unsigned char* LB = LA + 32768;
    short8 a0[4][2], a1[4][2], b[NH2][2];

    // issue all reads up-front; stage B(t+1) interleaved
    READ_A(0, a0);                       // 8
    READ_BR(0, NB0, b);                  // 2*NB0
    if (t + 1 < NT) STAGE_B(t + 1, cur ^ 1);
    READ_BR(NB0, NB1, b);                // 2*NB1
    READ_A(1, a1);                       // 8

    LGKMC(12);                           // a0 + b_lo landed (both NH2)
    CLUSTER(0, 0, NB0, a0, b);
    LGKMC(8);                            // b_hi landed (both NH2)
    CLUSTER(0, NB0, NB1, a0, b);
    LGKMC(0);                            // a1 landed (all reads drained)
    CLUSTER(1, 0, NB0, a1, b);
    BARR;                                // all waves drained -> cur writable
    if (t + 2 < NT) STAGE_A(t + 2, cur);
    CLUSTER(1, NB0, NB1, a1, b);         // register-only, overlaps stage
    if (t + 2 < NT) { VMC(4); } else { VMC(0); }
    BARR;
  }

#pragma unroll
  for (int mh = 0; mh < 2; ++mh)
#pragma unroll
    for (int m = 0; m < 4; ++m)
#pragma unroll
      for (int n2 = 0; n2 < NH2; ++n2)
#pragma unroll
        for (int i = 0; i < 4; ++i) {
          int row = m0 + wm * 128 + mh * 64 + m * 16 + li4 + i;
          int col = n0 + wn * (16 * NH2) + n2 * 16 + lr;
          float v = acc[mh * 4 + m][n2][i];
          if constexpr (sizeof(OutT) == 2)
            C[(size_t)row * N + col] = (OutT)f2b(v);
          else
            C[(size_t)row * N + col] = (OutT)v;
        }
}

// ---------- RoPE + split: QKV bf16 [T][8192] -> Q[h][t][d], K[h][t][d] (bf16) ----------

__global__ __launch_bounds__(256) void k_rope(const unsigned short* __restrict__ qkv,
                                              const float* __restrict__ cs,
                                              const float* __restrict__ sn,
                                              unsigned short* __restrict__ Q,
                                              unsigned short* __restrict__ K) {
  const int t = blockIdx.x;
  const int tid = threadIdx.x;
  const unsigned short* row = qkv + (size_t)t * QKVC;
  const float* c = cs + t * 64;
  const float* s = sn + t * 64;
  for (int p = tid; p < 56 * 16; p += 256) {
    const int h = p >> 4, q4 = (p & 15) * 4;
    const unsigned short* src = row + h * 128;
    union { unsigned short sh[4]; uint2 u; } x1u, x2u;
    x1u.u = *(const uint2*)(src + q4);
    x2u.u = *(const uint2*)(src + 64 + q4);
    float4 cc = *(const float4*)(c + q4);
    float4 ss = *(const float4*)(s + q4);
    unsigned short* dst = (h < NHEADS)
        ? Q + ((size_t)h * TSEQ + t) * HDIM
        : K + ((size_t)(h - NHEADS) * TSEQ + t) * HDIM;
    float x10 = b2f(x1u.sh[0]), x11 = b2f(x1u.sh[1]),
          x12 = b2f(x1u.sh[2]), x13 = b2f(x1u.sh[3]);
    float x20 = b2f(x2u.sh[0]), x21 = b2f(x2u.sh[1]),
          x22 = b2f(x2u.sh[2]), x23 = b2f(x2u.sh[3]);
    union { unsigned short sh[4]; uint2 u; } o1, o2;
    o1.sh[0] = f2b(x10 * cc.x - x20 * ss.x);
    o1.sh[1] = f2b(x11 * cc.y - x21 * ss.y);
    o1.sh[2] = f2b(x12 * cc.z - x22 * ss.z);
    o1.sh[3] = f2b(x13 * cc.w - x23 * ss.w);
    o2.sh[0] = f2b(x20 * cc.x + x10 * ss.x);
    o2.sh[1] = f2b(x21 * cc.y + x11 * ss.y);
    o2.sh[2] = f2b(x22 * cc.z + x12 * ss.z);
    o2.sh[3] = f2b(x23 * cc.w + x13 * ss.w);
    *(uint2*)(dst + q4) = o1.u;
    *(uint2*)(dst + 64 + q4) = o2.u;
  }
}

// ---------- attention: balanced pairs + double-buffered gload_lds pipeline ----------
// (round-12 verified version: stage(st+1) issued before compute(st); raw
// s_barrier + explicit VMC(0) after compute so load latency hides under the
// ~600cyc compute phase. LDS 72KB -> 2 blocks/CU.)

__global__ __launch_bounds__(256, 2) void k_attn3(const unsigned short* __restrict__ Q,
                                                  const unsigned short* __restrict__ K,
                                                  const unsigned short* __restrict__ V,  // Vt[h][d][t]
                                                  unsigned short* __restrict__ O) {
  __shared__ __align__(16) unsigned char KsB[2][16384];   // 64 s-rows x 256 B (swizzled)
  __shared__ __align__(16) unsigned char VsB[2][16384];   // 128 d-rows x 128 B (swizzled)
  __shared__ __align__(16) unsigned char PsB[4][2048];    // per-wave 16 q-rows x 128 B (swizzled)

  const int lin = blockIdx.x;
  const int g   = lin & 7;            // kv head == XCD hint
  const int rr  = lin >> 3;           // 0..95
  const int hg  = rr % 6;
  const int pr  = rr / 6;             // 0..15
  const int h   = g * 6 + hg;
  const int tid = threadIdx.x, wave = tid >> 6, lane = tid & 63;
  const int lr = lane & 15, lk = (lane >> 4) * 8, li4 = (lane >> 4) * 4;
  const unsigned short* Qh = Q + (size_t)h * (TSEQ * HDIM);
  const unsigned char*  Kb = (const unsigned char*)(K + (size_t)g * (TSEQ * HDIM));
  const unsigned char*  Vb = (const unsigned char*)(V + (size_t)g * (TSEQ * HDIM));
  unsigned char* Pw = PsB[wave];

#define STAGE_KV(st_, b_) do { \
  const int s_ = (st_) * 64; \
  _Pragma("unroll") for (int c = 0; c < 4; ++c) { \
    const int FF = tid * 16 + c * 4096; \
    const int krow = FF >> 8; \
    const int kcol = (FF & 255) ^ ((krow & 7) << 4); \
    gload_lds16(Kb + (size_t)(s_ + krow) * 256 + kcol, KsB[b_] + FF); \
    const int vrow = FF >> 7; \
    const int vcol = (FF & 127) ^ ((vrow & 7) << 4); \
    gload_lds16(Vb + (size_t)vrow * (TSEQ * 2) + (size_t)s_ * 2 + vcol, VsB[b_] + FF); \
  } } while (0)

  for (int half = 0; half < 2; ++half) {
    const int j  = half ? (31 - pr) : pr;     // q-tile index (64 rows)
    const int t0 = j * 64 + wave * 16;        // this wave's 16 rows
    const int nst = j + 1;

    short8 qf[4];
#pragma unroll
    for (int ks = 0; ks < 4; ++ks)
      qf[ks] = *(const short8*)(Qh + (size_t)(t0 + lr) * HDIM + ks * 32 + lk);

    f32x4 oacc[8];
#pragma unroll
    for (int n = 0; n < 8; ++n) oacc[n] = (f32x4){0.f, 0.f, 0.f, 0.f};
    float rs4[4] = {0.f, 0.f, 0.f, 0.f};

    STAGE_KV(0, 0);
    VMC(0);
    BARR;

    for (int st = 0; st < nst; ++st) {
      const int cur = st & 1;
      if (st + 1 < nst) STAGE_KV(st + 1, cur ^ 1);

      const unsigned char* Ks = KsB[cur];
      const unsigned char* Vs = VsB[cur];
      const int s0 = st * 64;
      f32x4 sacc[4];
#pragma unroll
      for (int n = 0; n < 4; ++n) sacc[n] = (f32x4){0.f, 0.f, 0.f, 0.f};
#pragma unroll
      for (int ks = 0; ks < 4; ++ks) {
        short8 kf[4];
#pragma unroll
        for (int n = 0; n < 4; ++n) {
          const int row = n * 16 + lr;
          kf[n] = *(const short8*)(Ks + row * 256 + ((ks * 64 + lk * 2) ^ ((row & 7) << 4)));
        }
#pragma unroll
        for (int n = 0; n < 4; ++n)
          sacc[n] = __builtin_amdgcn_mfma_f32_16x16x32_bf16(qf[ks], kf[n], sacc[n], 0, 0, 0);
      }

      const bool lastst = (st == nst - 1);
#pragma unroll
      for (int n = 0; n < 4; ++n)
#pragma unroll
        for (int i = 0; i < 4; ++i) {
          float sv = sacc[n][i] * 0.08838834764831845f;   // 1/sqrt(128)
          float e = EXP2(sv * 0.09617966939259757f);       // e^(s/15)
          float p = EXP2(-86.5617024533378f * RCP(e + 1.0f));
          if (lastst && (s0 + n * 16 + lr > t0 + li4 + i)) p = 0.f;
          rs4[i] += p;
          const int prow = li4 + i;
          *(unsigned short*)(Pw + prow * 128 +
              (((n * 16 + lr) * 2) ^ ((prow & 7) << 4))) = f2b(p);
        }

#pragma unroll
      for (int ks2 = 0; ks2 < 2; ++ks2) {
        short8 pf = *(const short8*)(Pw + lr * 128 +
                         (((ks2 * 32 + lk) * 2) ^ ((lr & 7) << 4)));
        short8 vf[8];
#pragma unroll
        for (int n = 0; n < 8; ++n) {
          const int row = n * 16 + lr;
          vf[n] = *(const short8*)(Vs + row * 128 + ((ks2 * 64 + lk * 2) ^ ((row & 7) << 4)));
        }
#pragma unroll
        for (int n = 0; n < 8; ++n)
          oacc[n] = __builtin_amdgcn_mfma_f32_16x16x32_bf16(pf, vf[n], oacc[n], 0, 0, 0);
      }

      VMC(0);     // drain next-step staging (hidden under compute above)
      BARR;
    }

    float inv4[4];
#pragma unroll
    for (int i = 0; i < 4; ++i) {
      float v = rs4[i];
      v += __shfl_xor(v, 1, 64);
      v += __shfl_xor(v, 2, 64);
      v += __shfl_xor(v, 4, 64);
      v += __shfl_xor(v, 8, 64);
      inv4[i] = RCP(v);
    }
#pragma unroll
    for (int n = 0; n < 8; ++n)
#pragma unroll
      for (int i = 0; i < 4; ++i)
        O[(size_t)(t0 + li4 + i) * DMODEL + h * HDIM + n * 16 + lr] =
            f2b(oacc[n][i] * inv4[i]);
    BARR;   // protect LDS before next half re-stages buf 0
  }
#undef STAGE_KV
}

// ---------- launch ----------

extern "C" void kernel_launch(void* const* d_in, const int* in_sizes, int n_in,
                              void* d_out, int out_size, void* d_ws, size_t ws_size,
                              hipStream_t stream) {
  const int*   pos  = (const int*)d_in[0];
  const float* hid  = (const float*)d_in[1];
  const float* wqkv = (const float*)d_in[2];
  const float* wo   = (const float*)d_in[3];
  float* out = (float*)d_out;
  char* ws = (char*)d_ws;

  const size_t O_XB   = 0;                         // Xb bf16 [2048][6144]; later attn_out
  const size_t O_WQT  = 25165824;                  // Wqkv^T bf16 [8192][6144]; later Q/K/Vt
  const size_t O_WOT  = 125829120;                 // Wo^T bf16 [6144][6144]
  const size_t O_QKV  = 201326592;                 // QKV bf16 [2048][8192]
  const size_t O_TRIG = 268435456;                 // cos/sin f32 [2048][64] each

  unsigned short* Xb  = (unsigned short*)(ws + O_XB);
  unsigned short* Wqt = (unsigned short*)(ws + O_WQT);
  unsigned short* Wot = (unsigned short*)(ws + O_WOT);
  unsigned short* QKVb = (unsigned short*)(ws + O_QKV);
  float* CS  = (float*)(ws + O_TRIG);
  float* SN  = CS + TSEQ * 64;
  unsigned short* Qr = Wqt;                                  // [48][2048][128]
  unsigned short* Kr = Wqt + (size_t)NHEADS * TSEQ * HDIM;   // [8][2048][128]
  unsigned short* Vt = Kr + (size_t)NKVH * TSEQ * HDIM;      // [8][128][2048]
  unsigned short* AO = Xb;                                   // attn_out bf16 [2048][6144]

  hipFuncSetAttribute((const void*)k_gemm8<4, unsigned short>,
                      hipFuncAttributeMaxDynamicSharedMemorySize, 131072);
  hipFuncSetAttribute((const void*)k_gemm8<3, float>,
                      hipFuncAttributeMaxDynamicSharedMemorySize, 114688);

  k_cvt<<<(TSEQ * DMODEL) / (256 * 8), 256, 0, stream>>>(hid, Xb, TSEQ * DMODEL);
  // Wqkv^T: in 6144x8192 -> out 8192x6144
  k_tr2<<<dim3(QKVC / 64, DMODEL / 64, 1), 256, 0, stream>>>(wqkv, QKVC, 0, Wqt, DMODEL, 0);
  // Wo^T: in 6144x6144 -> out 6144x6144
  k_tr2<<<dim3(DMODEL / 64, DMODEL / 64, 1), 256, 0, stream>>>(wo, DMODEL, 0, Wot, DMODEL, 0);
  k_trig<<<TSEQ, 64, 0, stream>>>(pos, CS, SN);

  // GEMM1: BN=256 (BUFSZ=65536, LDS 131072 = round-9 layout), grid 256 = 1/CU.
  k_gemm8<4, unsigned short><<<(TSEQ / 256) * (QKVC / 256), 512, 131072, stream>>>(
      Xb, Wqt, QKVb, TSEQ, QKVC, DMODEL);
  k_rope<<<TSEQ, 256, 0, stream>>>(QKVb, CS, SN, Qr, Kr);
  // Vt: per head z, in QKVb[t][7168 + z*128 + d] (2048x128 bf16) -> Vt[z][d][t]
  k_tr2b<<<dim3(HDIM / 64, TSEQ / 64, NKVH), 256, 0, stream>>>(
      QKVb + (size_t)(DMODEL + NKVH * HDIM), QKVC, HDIM,
      Vt, TSEQ, (size_t)HDIM * TSEQ);
  k_attn3<<<768, 256, 0, stream>>>(Qr, Kr, Vt, AO);
  // GEMM2: BN=192 (BUFSZ=57344, LDS 114688), grid 8*32 = 256 blocks = 1/CU.
  k_gemm8<3, float><<<(TSEQ / 256) * (DMODEL / 192), 512, 114688, stream>>>(
      AO, Wot, out, TSEQ, DMODEL, DMODEL);
}